// Round 7
// baseline (4594.601 us; speedup 1.0000x reference)
//
#include <hip/hip_runtime.h>
#include <cstdint>
#include <cstddef>

// Problem constants (from reference)
#define T_STEPS 16
#define AA 64
#define BBX 64
#define NF 12            // N attention filters
#define BATCH 4096
#define ZS 100
#define ENC 400
#define DEC 400
#define IMG (AA*BBX)     // 4096
#define RDIM (2*NF*NF)   // 288
#define GDIM (4*ENC)     // 1600

// Padded GEMM operand geometry (all K multiples of 32, N multiples of 128)
#define KENC 1088        // [r 0:288 | h_dec 288:688 | h_enc 688:1088]
#define KDEC 544         // [z 0:100 | pad | h_dec 128:528 | pad]
#define KSML 416         // mus / wvec GEMMs (real K=400)
#define NBIG 1664        // padded rows for enc/dec weight B (real 1600)
#define NSML 256         // padded rows for mus/wrt B

typedef __attribute__((ext_vector_type(8))) short bfrag;    // 8 x bf16 (4 VGPRs)
typedef __attribute__((ext_vector_type(4))) float f32x4;

__device__ __forceinline__ float sigmoidf_(float v) { return 1.f / (1.f + expf(-v)); }

__device__ __forceinline__ float bf2f(unsigned short u) {
    uint32_t x = ((uint32_t)u) << 16;
    return __builtin_bit_cast(float, x);
}

// fp32 -> (bf16_hi, bf16_lo) split, RTN-even. f ~= hi + lo, residual ~2^-18|f|.
__device__ __forceinline__ void split2(float f, unsigned short& h, unsigned short& l) {
    uint32_t u = __builtin_bit_cast(uint32_t, f);
    uint32_t hb = (u + 0x7FFFu + ((u >> 16) & 1u)) >> 16;
    float hf = __builtin_bit_cast(float, hb << 16);
    float r = f - hf;
    uint32_t v = __builtin_bit_cast(uint32_t, r);
    uint32_t lb = (v + 0x7FFFu + ((v >> 16) & 1u)) >> 16;
    h = (unsigned short)hb;
    l = (unsigned short)lb;
}

// LDS-only barrier: does NOT drain vmcnt, so async global_load_lds prefetch
// issued earlier stays in flight across attention compute (T4-style).
__device__ __forceinline__ void bar_lds() {
    asm volatile("s_waitcnt lgkmcnt(0)" ::: "memory");
    __builtin_amdgcn_s_barrier();
    __builtin_amdgcn_sched_barrier(0);
}

// ---------------------------------------------------------------------------
// Split-bf16 MFMA GEMM, pre-split operands (no conversion in hot loop).
// C[4096 x NN] = A @ B^T + b1(+b2);  A,B given as separate bf16 hi/lo planes.
//   ah*bh + ah*bl + al*bh  (3 products; al*bl ~2^-18 relative, dropped)
// Tile 128x128x32, 256 thr = 4 waves (2x2), wave tile 64x64 = 4x4 frags of
// mfma_f32_16x16x32_bf16. LDS fragment-linear 16x32 subtiles (see R3 notes).
// ---------------------------------------------------------------------------
__global__ __launch_bounds__(256, 2) void k_gemm2(
    const unsigned short* __restrict__ Ah, const unsigned short* __restrict__ Al,
    int lda, int a_off,
    const unsigned short* __restrict__ Bh, const unsigned short* __restrict__ Bl,
    int Kpad,
    const float* __restrict__ b1, const float* __restrict__ b2,
    float* __restrict__ C, int NN)
{
    __shared__ unsigned short lA[2][8 * 512];   // [hi/lo][sub*512 + lane*8] : 16 KiB
    __shared__ unsigned short lB[2][8 * 512];   // 16 KiB

    const int tid = threadIdx.x;
    const int lane = tid & 63;
    const int wave = tid >> 6;
    const int wr = wave >> 1;                   // wave row (64 m)
    const int wc = wave & 1;                    // wave col (64 n)
    const int m0 = blockIdx.y * 128;
    const int n0 = blockIdx.x * 128;
    const int rlow = lane & 15;
    const int kg8 = (lane >> 4) * 8;

    // per-wave staging source (wave 0:A-hi 1:A-lo 2:B-hi 3:B-lo)
    const size_t aBase = (size_t)(m0 + rlow) * lda + a_off + kg8;
    const size_t bBase = (size_t)(n0 + rlow) * Kpad + kg8;
    const unsigned short* gsrc;
    unsigned short* ldst;
    size_t stride16;                            // 16 rows, in elements
    if (wave == 0)      { gsrc = Ah + aBase; ldst = &lA[0][0]; stride16 = (size_t)lda * 16; }
    else if (wave == 1) { gsrc = Al + aBase; ldst = &lA[1][0]; stride16 = (size_t)lda * 16; }
    else if (wave == 2) { gsrc = Bh + bBase; ldst = &lB[0][0]; stride16 = (size_t)Kpad * 16; }
    else                { gsrc = Bl + bBase; ldst = &lB[1][0]; stride16 = (size_t)Kpad * 16; }

    f32x4 acc[4][4];
#pragma unroll
    for (int mf = 0; mf < 4; ++mf)
#pragma unroll
        for (int nf = 0; nf < 4; ++nf) acc[mf][nf] = (f32x4){0.f, 0.f, 0.f, 0.f};

    for (int k0 = 0; k0 < Kpad; k0 += 32) {
#pragma unroll
        for (int sub = 0; sub < 8; ++sub) {
            __builtin_amdgcn_global_load_lds(
                (const __attribute__((address_space(1))) void*)(gsrc + (size_t)sub * stride16 + k0),
                (__attribute__((address_space(3))) void*)(ldst + sub * 512), 16, 0, 0);
        }
        __syncthreads();   // drains own vmcnt before barrier -> LDS visible to all

        bfrag bhf[4], blf[4];
#pragma unroll
        for (int nf = 0; nf < 4; ++nf) {
            bhf[nf] = *(const bfrag*)&lB[0][(wc * 4 + nf) * 512 + lane * 8];
            blf[nf] = *(const bfrag*)&lB[1][(wc * 4 + nf) * 512 + lane * 8];
        }
#pragma unroll
        for (int mf = 0; mf < 4; ++mf) {
            const bfrag ah = *(const bfrag*)&lA[0][(wr * 4 + mf) * 512 + lane * 8];
            const bfrag al = *(const bfrag*)&lA[1][(wr * 4 + mf) * 512 + lane * 8];
#pragma unroll
            for (int nf = 0; nf < 4; ++nf) {
                acc[mf][nf] = __builtin_amdgcn_mfma_f32_16x16x32_bf16(ah, bhf[nf], acc[mf][nf], 0, 0, 0);
                acc[mf][nf] = __builtin_amdgcn_mfma_f32_16x16x32_bf16(ah, blf[nf], acc[mf][nf], 0, 0, 0);
                acc[mf][nf] = __builtin_amdgcn_mfma_f32_16x16x32_bf16(al, bhf[nf], acc[mf][nf], 0, 0, 0);
            }
        }
        __syncthreads();
    }

    // epilogue: C layout col=lane&15, row=(lane>>4)*4+j
    const int col = lane & 15;
    const int rowq = (lane >> 4) * 4;
#pragma unroll
    for (int nf = 0; nf < 4; ++nf) {
        const int n = n0 + wc * 64 + nf * 16 + col;
        if (n < NN) {
            float bb = b1[n];
            if (b2) bb += b2[n];
#pragma unroll
            for (int mf = 0; mf < 4; ++mf) {
                const int mbase = m0 + wr * 64 + mf * 16 + rowq;
#pragma unroll
                for (int j = 0; j < 4; ++j)
                    C[(size_t)(mbase + j) * NN + n] = acc[mf][nf][j] + bb;
            }
        }
    }
}

// ---------------------------------------------------------------------------
// Weight pre-split: dst[(row0+r)*ld + col0 + c] = split(src[r*cols+c])
// ---------------------------------------------------------------------------
__global__ __launch_bounds__(256) void k_fillw(
    const float* __restrict__ src, int rows, int cols,
    unsigned short* __restrict__ dh, unsigned short* __restrict__ dl,
    int ld, int col0, int row0)
{
    const int i = blockIdx.x * 256 + threadIdx.x;
    if (i >= rows * cols) return;
    const int r = i / cols, c = i - r * cols;
    unsigned short h, l;
    split2(src[i], h, l);
    dh[(size_t)(row0 + r) * ld + col0 + c] = h;
    dl[(size_t)(row0 + r) * ld + col0 + c] = l;
}

// ---------------------------------------------------------------------------
// Attention filterbank (full-sync flavor, for k_glimpse / k_write).
// ---------------------------------------------------------------------------
__device__ __forceinline__ void attn_compute(
    const float* __restrict__ hd,
    const float* __restrict__ w_attn, const float* __restrict__ b_attn,
    float* __restrict__ p,
    float (* __restrict__ Fx)[68], float (* __restrict__ Fy)[68],
    float* __restrict__ rowinv)
{
    const int t = threadIdx.x;
    const int lane = t & 63, wave = t >> 6;
    for (int o = wave; o < 5; o += 4) {
        float s = 0.f;
        for (int k = lane; k < DEC; k += 64) s += hd[k] * w_attn[o * DEC + k];
#pragma unroll
        for (int off = 32; off; off >>= 1) s += __shfl_down(s, off);
        if (lane == 0) p[o] = s + b_attn[o];
    }
    __syncthreads();
    const float gx = 32.5f * (p[0] + 1.f);
    const float gy = 32.5f * (p[1] + 1.f);
    const float sigma2 = expf(p[2]);
    const float delta = (63.f / 11.f) * expf(p[3]);
    const float inv2s = 1.f / (2.f * sigma2);
    for (int e = t; e < NF * 64; e += 256) {
        const int n = e >> 6, a = e & 63;
        const float mu_x = ((float)n - 6.5f) * delta + gx;
        const float mu_y = ((float)n - 6.5f) * delta + gy;
        const float tx = ((float)a - mu_x) * inv2s;
        const float ty = ((float)a - mu_y) * inv2s;
        Fx[n][a] = expf(-tx * tx);
        Fy[n][a] = expf(-ty * ty);
    }
    __syncthreads();
    for (int rix = wave; rix < 24; rix += 4) {
        const float* row = (rix < 12) ? &Fx[rix][0] : &Fy[rix - 12][0];
        float s = row[lane];
#pragma unroll
        for (int off = 32; off; off >>= 1) s += __shfl_down(s, off);
        if (lane == 0) rowinv[rix] = 1.f / (s + 1e-9f);
    }
    __syncthreads();
    for (int e = t; e < NF * 64; e += 256) {
        const int n = e >> 6, a = e & 63;
        Fx[n][a] *= rowinv[n];
        Fy[n][a] *= rowinv[12 + n];
    }
}

// ---------------------------------------------------------------------------
// Glimpse (step 0 only): attn(h_dec) then r = [g*Fy@x@Fx^T, g*Fy@x_hat@Fx^T]
// ---------------------------------------------------------------------------
__global__ __launch_bounds__(256) void k_glimpse(
    const float* __restrict__ x, const float* __restrict__ c,
    unsigned short* __restrict__ eAh, unsigned short* __restrict__ eAl,
    const float* __restrict__ w_attn, const float* __restrict__ b_attn)
{
    __shared__ __align__(16) float hd[DEC];
    __shared__ __align__(16) float p[8];
    __shared__ __align__(16) float Fx[NF][68], Fy[NF][68];
    __shared__ __align__(16) float rowinv[24];
    __shared__ __align__(16) float img[IMG], imgh[IMG];
    __shared__ __align__(16) float tmp1[NF][68], tmp2[NF][68];
    const int item = blockIdx.x;
    const int t = threadIdx.x;
    const size_t arow = (size_t)item * KENC;

    for (int i = t; i < DEC; i += 256)
        hd[i] = bf2f(eAh[arow + 288 + i]) + bf2f(eAl[arow + 288 + i]);
    __syncthreads();
    attn_compute(hd, w_attn, b_attn, p, Fx, Fy, rowinv);

    for (int i = t; i < IMG; i += 256) {
        const float xv = x[(size_t)item * IMG + i];
        const float cv = c[(size_t)item * IMG + i];
        img[i] = xv;
        imgh[i] = xv - sigmoidf_(cv);
    }
    __syncthreads();
    const float gamma = expf(p[4]);

    if (t < 192) {
        const int n = t >> 4, a0 = (t & 15) * 4;
        float s10 = 0, s11 = 0, s12 = 0, s13 = 0;
        float s20 = 0, s21 = 0, s22 = 0, s23 = 0;
        for (int Bi = 0; Bi < 64; ++Bi) {
            const float fy = Fy[n][Bi];
            const float4 v1 = *(const float4*)&img[Bi * 64 + a0];
            const float4 v2 = *(const float4*)&imgh[Bi * 64 + a0];
            s10 += fy * v1.x; s11 += fy * v1.y; s12 += fy * v1.z; s13 += fy * v1.w;
            s20 += fy * v2.x; s21 += fy * v2.y; s22 += fy * v2.z; s23 += fy * v2.w;
        }
        *(float4*)&tmp1[n][a0] = make_float4(s10, s11, s12, s13);
        *(float4*)&tmp2[n][a0] = make_float4(s20, s21, s22, s23);
    }
    __syncthreads();

    for (int e = t; e < 2 * NF * NF; e += 256) {
        const int which = e / 144;
        const int idx = e - which * 144;
        const int n = idx / 12, m = idx - (idx / 12) * 12;
        const float (*tp)[68] = which ? tmp2 : tmp1;
        const float4* tv = (const float4*)&tp[n][0];
        const float4* fv = (const float4*)&Fx[m][0];
        float s = 0.f;
#pragma unroll
        for (int a4 = 0; a4 < 16; ++a4) {
            const float4 tvv = tv[a4], fvv = fv[a4];
            s += tvv.x * fvv.x + tvv.y * fvv.y + tvv.z * fvv.z + tvv.w * fvv.w;
        }
        unsigned short vh, vl;
        split2(s * gamma, vh, vl);
        eAh[arow + e] = vh;
        eAl[arow + e] = vl;
    }
}

// ---------------------------------------------------------------------------
// FUSED write(t) + glimpse(t+1), MFMA glimpse contraction.
//   p0: canvas -> regs (async), x -> LDS (global_load_lds), h_dec/wvec -> LDS
//   p1: attn (lgkm barriers): Fx f32, Fy f32 (16-row, pad zeroed); u = Fy^T w
//   p2: [full sync: vmcnt drained] c_new = c_reg + wr/gamma -> global;
//       imgh = x - sigmoid(c_new) -> LDS f32
//   p3: tmp1 = Fy@x, tmp2 = Fy@imgh via mfma_16x16x32_bf16, split-bf16
//       3-product; operand frags built in registers (scalar LDS + split2).
//       Wave w owns a-tile w; A=Fy rows, W=img^T rows (k_gemm2 convention).
//   p4: r[which][n][m] = gamma * sum_a tmp[n][a] Fx[m][a] -> encA bf16 hi/lo
// ---------------------------------------------------------------------------
__global__ __launch_bounds__(256) void k_wrgl(
    const float* __restrict__ x, float* __restrict__ c,
    unsigned short* __restrict__ eAh, unsigned short* __restrict__ eAl,
    const float* __restrict__ w_attn, const float* __restrict__ b_attn,
    const float* __restrict__ wvec)
{
    __shared__ __align__(16) float xx[64][64];    // x   (16 KiB)
    __shared__ __align__(16) float gg[64][64];    // x_hat (16 KiB)
    __shared__ __align__(16) float Fyf[16][68];   // Fy f32, rows 12-15 zero
    __shared__ __align__(16) float Fx[NF][68];
    __shared__ __align__(16) float tmp[2][NF][68];
    __shared__ __align__(16) float u[64][13];
    __shared__ __align__(16) float hd[DEC];
    __shared__ __align__(16) float p[8];
    __shared__ __align__(16) float rowinv[24];
    __shared__ __align__(16) float wsv[NF * NF];
    const int item = blockIdx.x;
    const int t = threadIdx.x;
    const int lane = t & 63, wave = t >> 6;
    const size_t arow = (size_t)item * KENC;

    // --- p0: canvas to regs, x to LDS (async), h_dec/wvec to LDS ---
    float4 cv4[4];
#pragma unroll
    for (int j = 0; j < 4; ++j)
        cv4[j] = *(const float4*)&c[(size_t)item * IMG + j * 1024 + t * 4];
    {
        const float* xsrc = x + (size_t)item * IMG + wave * 1024 + lane * 4;
        float* xdst = &xx[0][0] + wave * 1024;
#pragma unroll
        for (int j = 0; j < 4; ++j)
            __builtin_amdgcn_global_load_lds(
                (const __attribute__((address_space(1))) void*)(xsrc + j * 256),
                (__attribute__((address_space(3))) void*)(xdst + j * 256), 16, 0, 0);
    }
    {
        float hdv0 = bf2f(eAh[arow + 288 + t]) + bf2f(eAl[arow + 288 + t]);
        hd[t] = hdv0;
        if (t + 256 < DEC)
            hd[t + 256] = bf2f(eAh[arow + 288 + t + 256]) + bf2f(eAl[arow + 288 + t + 256]);
        if (t < NF * NF) wsv[t] = wvec[(size_t)item * (NF * NF) + t];
    }
    bar_lds();

    // --- p1: attention (lgkm-only barriers) ---
    for (int o = wave; o < 5; o += 4) {
        float s = 0.f;
        for (int k = lane; k < DEC; k += 64) s += hd[k] * w_attn[o * DEC + k];
#pragma unroll
        for (int off = 32; off; off >>= 1) s += __shfl_down(s, off);
        if (lane == 0) p[o] = s + b_attn[o];
    }
    bar_lds();
    {
        const float gx = 32.5f * (p[0] + 1.f);
        const float gy = 32.5f * (p[1] + 1.f);
        const float sigma2 = expf(p[2]);
        const float delta = (63.f / 11.f) * expf(p[3]);
        const float inv2s = 1.f / (2.f * sigma2);
        for (int e = t; e < NF * 64; e += 256) {
            const int n = e >> 6, a = e & 63;
            const float mu_x = ((float)n - 6.5f) * delta + gx;
            const float mu_y = ((float)n - 6.5f) * delta + gy;
            const float tx = ((float)a - mu_x) * inv2s;
            const float ty = ((float)a - mu_y) * inv2s;
            Fx[n][a] = expf(-tx * tx);
            Fyf[n][a] = expf(-ty * ty);
        }
        for (int e = t; e < 4 * 68; e += 256)       // zero Fy pad rows 12-15
            Fyf[12 + e / 68][e - (e / 68) * 68] = 0.f;
    }
    bar_lds();
    for (int rix = wave; rix < 24; rix += 4) {
        const float* row = (rix < 12) ? &Fx[rix][0] : &Fyf[rix - 12][0];
        float s = row[lane];
#pragma unroll
        for (int off = 32; off; off >>= 1) s += __shfl_down(s, off);
        if (lane == 0) rowinv[rix] = 1.f / (s + 1e-9f);
    }
    bar_lds();
    for (int e = t; e < NF * 64; e += 256) {
        const int n = e >> 6, a = e & 63;
        Fx[n][a] *= rowinv[n];
        Fyf[n][a] *= rowinv[12 + n];
    }
    bar_lds();
    const float gamma = expf(p[4]);
    const float ginv = 1.f / gamma;
    for (int e = t; e < 64 * NF; e += 256) {
        const int Bb = e / 12, m = e - (e / 12) * 12;
        float s = 0.f;
#pragma unroll
        for (int n = 0; n < 12; ++n) s += Fyf[n][Bb] * wsv[n * 12 + m];
        u[Bb][m] = s;
    }

    // --- p2: canvas update (regs) + imgh f32 (full sync drains x prefetch) ---
    __syncthreads();
#pragma unroll
    for (int j = 0; j < 4; ++j) {
        const int i0 = j * 1024 + t * 4;
        const int Bb = i0 >> 6, a0 = i0 & 63;
        float s0 = 0, s1 = 0, s2 = 0, s3 = 0;
#pragma unroll
        for (int m = 0; m < 12; ++m) {
            const float um = u[Bb][m];
            s0 += um * Fx[m][a0];     s1 += um * Fx[m][a0 + 1];
            s2 += um * Fx[m][a0 + 2]; s3 += um * Fx[m][a0 + 3];
        }
        const float4 cn = make_float4(cv4[j].x + s0 * ginv, cv4[j].y + s1 * ginv,
                                      cv4[j].z + s2 * ginv, cv4[j].w + s3 * ginv);
        *(float4*)&c[(size_t)item * IMG + i0] = cn;
        const float4 xv = *(const float4*)&xx[Bb][a0];
        *(float4*)&gg[Bb][a0] = make_float4(
            xv.x - sigmoidf_(cn.x), xv.y - sigmoidf_(cn.y),
            xv.z - sigmoidf_(cn.z), xv.w - sigmoidf_(cn.w));
    }
    bar_lds();

    // --- p3: MFMA glimpse contraction. Wave w = a-tile w. ---
    {
        const int at = wave;                       // a-tile 0..3
        const int arow16 = at * 16 + (lane & 15);  // W-row: a
        const int nrow = lane & 15;                // A-row: filter n
        const int kb0 = (lane >> 4) * 8;
        f32x4 acc1 = (f32x4){0.f, 0.f, 0.f, 0.f};
        f32x4 acc2 = (f32x4){0.f, 0.f, 0.f, 0.f};
#pragma unroll
        for (int ksub = 0; ksub < 2; ++ksub) {
            const int kb = ksub * 32 + kb0;
            bfrag fh, fl, xh, xl, gh, gl;
#pragma unroll
            for (int e = 0; e < 8; ++e) {
                unsigned short h, l;
                split2(Fyf[nrow][kb + e], h, l); fh[e] = (short)h; fl[e] = (short)l;
                split2(xx[kb + e][arow16], h, l); xh[e] = (short)h; xl[e] = (short)l;
                split2(gg[kb + e][arow16], h, l); gh[e] = (short)h; gl[e] = (short)l;
            }
            acc1 = __builtin_amdgcn_mfma_f32_16x16x32_bf16(fh, xh, acc1, 0, 0, 0);
            acc1 = __builtin_amdgcn_mfma_f32_16x16x32_bf16(fh, xl, acc1, 0, 0, 0);
            acc1 = __builtin_amdgcn_mfma_f32_16x16x32_bf16(fl, xh, acc1, 0, 0, 0);
            acc2 = __builtin_amdgcn_mfma_f32_16x16x32_bf16(fh, gh, acc2, 0, 0, 0);
            acc2 = __builtin_amdgcn_mfma_f32_16x16x32_bf16(fh, gl, acc2, 0, 0, 0);
            acc2 = __builtin_amdgcn_mfma_f32_16x16x32_bf16(fl, gh, acc2, 0, 0, 0);
        }
        const int acol = at * 16 + (lane & 15);    // C col = W row = a
#pragma unroll
        for (int j = 0; j < 4; ++j) {
            const int n = (lane >> 4) * 4 + j;     // C row = A row = n
            if (n < 12) {
                tmp[0][n][acol] = acc1[j];
                tmp[1][n][acol] = acc2[j];
            }
        }
    }
    bar_lds();

    // --- p4: r = gamma * tmp @ Fx^T -> encA bf16 hi/lo ---
    for (int e = t; e < 2 * NF * NF; e += 256) {
        const int which = e / 144;
        const int idx = e - which * 144;
        const int n = idx / 12, m = idx - (idx / 12) * 12;
        const float4* tv = (const float4*)&tmp[which][n][0];
        const float4* fv = (const float4*)&Fx[m][0];
        float s = 0.f;
#pragma unroll
        for (int a4 = 0; a4 < 16; ++a4) {
            const float4 tvv = tv[a4], fvv = fv[a4];
            s += tvv.x * fvv.x + tvv.y * fvv.y + tvv.z * fvv.z + tvv.w * fvv.w;
        }
        unsigned short vh, vl;
        split2(s * gamma, vh, vl);
        eAh[arow + e] = vh;
        eAl[arow + e] = vl;
    }
}

// ---------------------------------------------------------------------------
// LSTM elementwise; writes h as bf16 hi/lo into 1 or 2 cat-A destinations.
// ---------------------------------------------------------------------------
__global__ __launch_bounds__(256) void k_lstm(
    const float* __restrict__ gates, float* __restrict__ s,
    unsigned short* __restrict__ d1h, unsigned short* __restrict__ d1l, int ld1,
    unsigned short* __restrict__ d2h, unsigned short* __restrict__ d2l, int ld2)
{
    const int idx = blockIdx.x * 256 + threadIdx.x;
    if (idx >= BATCH * ENC) return;
    const int m = idx / ENC, n = idx - m * ENC;
    const float* g = gates + (size_t)m * GDIM;
    const float gi = g[n], gf = g[n + 400], gg = g[n + 800], go = g[n + 1200];
    const float cold = s[idx];
    const float c2 = sigmoidf_(gf) * cold + sigmoidf_(gi) * tanhf(gg);
    s[idx] = c2;
    const float h = sigmoidf_(go) * tanhf(c2);
    unsigned short hh, hl;
    split2(h, hh, hl);
    d1h[(size_t)m * ld1 + n] = hh;
    d1l[(size_t)m * ld1 + n] = hl;
    if (d2h) {
        d2h[(size_t)m * ld2 + n] = hh;
        d2l[(size_t)m * ld2 + n] = hl;
    }
}

// z = mu + exp(logsig)*eps -> decA cols 0:100 (hi/lo)
__global__ __launch_bounds__(256) void k_zelem(
    const float* __restrict__ mus, const float* __restrict__ eps_t,
    unsigned short* __restrict__ dzh, unsigned short* __restrict__ dzl)
{
    const int idx = blockIdx.x * 256 + threadIdx.x;
    if (idx >= BATCH * ZS) return;
    const int m = idx / ZS, o = idx - m * ZS;
    const float zv = mus[(size_t)m * 200 + o] + expf(mus[(size_t)m * 200 + 100 + o]) * eps_t[idx];
    unsigned short h, l;
    split2(zv, h, l);
    dzh[(size_t)m * KDEC + o] = h;
    dzl[(size_t)m * KDEC + o] = l;
}

// ---------------------------------------------------------------------------
// Write (final step only): attn(h_dec), wr = Fy^T @ w @ Fx / gamma, c += wr.
// ---------------------------------------------------------------------------
__global__ __launch_bounds__(256) void k_write(
    const unsigned short* __restrict__ eAh, const unsigned short* __restrict__ eAl,
    const float* __restrict__ w_attn, const float* __restrict__ b_attn,
    const float* __restrict__ wvec,
    float* __restrict__ c)
{
    __shared__ __align__(16) float hd[DEC];
    __shared__ __align__(16) float p[8];
    __shared__ __align__(16) float Fx[NF][68], Fy[NF][68];
    __shared__ __align__(16) float rowinv[24];
    __shared__ __align__(16) float wsv[NF * NF];
    __shared__ __align__(16) float u[64][13];
    const int item = blockIdx.x;
    const int t = threadIdx.x;
    const size_t arow = (size_t)item * KENC;

    for (int i = t; i < DEC; i += 256)
        hd[i] = bf2f(eAh[arow + 288 + i]) + bf2f(eAl[arow + 288 + i]);
    if (t < NF * NF) wsv[t] = wvec[(size_t)item * (NF * NF) + t];
    __syncthreads();
    attn_compute(hd, w_attn, b_attn, p, Fx, Fy, rowinv);
    __syncthreads();
    const float ginv = 1.f / expf(p[4]);

    for (int e = t; e < 64 * NF; e += 256) {
        const int Bb = e / 12, m = e - (e / 12) * 12;
        float s = 0.f;
#pragma unroll
        for (int n = 0; n < 12; ++n) s += Fy[n][Bb] * wsv[n * 12 + m];
        u[Bb][m] = s;
    }
    __syncthreads();
    for (int i = t; i < IMG; i += 256) {
        const int Bb = i >> 6, a = i & 63;
        float s = 0.f;
#pragma unroll
        for (int m = 0; m < 12; ++m) s += u[Bb][m] * Fx[m][a];
        c[(size_t)item * IMG + i] += s * ginv;
    }
}

// ---------------------------------------------------------------------------
extern "C" void kernel_launch(void* const* d_in, const int* in_sizes, int n_in,
                              void* d_out, int out_size, void* d_ws, size_t ws_size,
                              hipStream_t stream)
{
    const float* x        = (const float*)d_in[0];
    const float* eps      = (const float*)d_in[1];
    const float* w_enc_ih = (const float*)d_in[2];
    const float* w_enc_hh = (const float*)d_in[3];
    const float* b_enc_ih = (const float*)d_in[4];
    const float* b_enc_hh = (const float*)d_in[5];
    const float* w_dec_ih = (const float*)d_in[6];
    const float* w_dec_hh = (const float*)d_in[7];
    const float* b_dec_ih = (const float*)d_in[8];
    const float* b_dec_hh = (const float*)d_in[9];
    const float* w_mu     = (const float*)d_in[10];
    const float* b_mu     = (const float*)d_in[11];
    const float* w_sig    = (const float*)d_in[12];
    const float* b_sig    = (const float*)d_in[13];
    const float* w_attn   = (const float*)d_in[14];
    const float* b_attn   = (const float*)d_in[15];
    const float* w_write  = (const float*)d_in[16];
    const float* b_write  = (const float*)d_in[17];

    float* canvas = (float*)d_out;

    // ---- workspace layout (256B-aligned chunks) ----
    uint8_t* p = (uint8_t*)d_ws;
    auto nextu = [&](size_t elems) {
        unsigned short* r = (unsigned short*)p;
        p += (elems * 2 + 255) & ~(size_t)255;
        return r;
    };
    auto nextf = [&](size_t elems) {
        float* r = (float*)p;
        p += (elems * 4 + 255) & ~(size_t)255;
        return r;
    };
    uint8_t* zstart = p;
    unsigned short* encA_h = nextu((size_t)(BATCH + 1) * KENC);
    unsigned short* encA_l = nextu((size_t)(BATCH + 1) * KENC);
    unsigned short* decA_h = nextu((size_t)(BATCH + 1) * KDEC);
    unsigned short* decA_l = nextu((size_t)(BATCH + 1) * KDEC);
    unsigned short* encB_h = nextu((size_t)NBIG * KENC);
    unsigned short* encB_l = nextu((size_t)NBIG * KENC);
    unsigned short* decB_h = nextu((size_t)NBIG * KDEC);
    unsigned short* decB_l = nextu((size_t)NBIG * KDEC);
    unsigned short* musB_h = nextu((size_t)NSML * KSML);
    unsigned short* musB_l = nextu((size_t)NSML * KSML);
    unsigned short* wrtB_h = nextu((size_t)NSML * KSML);
    unsigned short* wrtB_l = nextu((size_t)NSML * KSML);
    float* s_enc = nextf((size_t)BATCH * ENC);
    float* s_dec = nextf((size_t)BATCH * DEC);
    float* b_cat = nextf(256);
    uint8_t* zend = p;
    float* gates = nextf((size_t)BATCH * GDIM);
    float* mus   = nextf((size_t)BATCH * 200);
    float* wvec  = nextf((size_t)BATCH * (NF * NF));

    hipMemsetAsync(zstart, 0, (size_t)(zend - zstart), stream);
    hipMemsetAsync(canvas, 0, (size_t)BATCH * IMG * sizeof(float), stream);

    // weight pre-split (runs every launch; ws is re-poisoned each call)
    auto fill = [&](const float* src, int rows, int cols,
                    unsigned short* dh, unsigned short* dl, int ld, int col0, int row0) {
        k_fillw<<<dim3((rows * cols + 255) / 256), 256, 0, stream>>>(
            src, rows, cols, dh, dl, ld, col0, row0);
    };
    fill(w_enc_ih, 1600, 688, encB_h, encB_l, KENC, 0, 0);
    fill(w_enc_hh, 1600, 400, encB_h, encB_l, KENC, 688, 0);
    fill(w_dec_ih, 1600, 100, decB_h, decB_l, KDEC, 0, 0);
    fill(w_dec_hh, 1600, 400, decB_h, decB_l, KDEC, 128, 0);
    fill(w_mu,     100, 400, musB_h, musB_l, KSML, 0, 0);
    fill(w_sig,    100, 400, musB_h, musB_l, KSML, 0, 100);
    fill(w_write,  144, 400, wrtB_h, wrtB_l, KSML, 0, 0);
    hipMemcpyAsync(b_cat,       b_mu,  100 * 4, hipMemcpyDeviceToDevice, stream);
    hipMemcpyAsync(b_cat + 100, b_sig, 100 * 4, hipMemcpyDeviceToDevice, stream);

    const dim3 blk(256);
    // glimpse for step 0 (h_dec=0, canvas=0)
    k_glimpse<<<BATCH, blk, 0, stream>>>(x, canvas, encA_h, encA_l, w_attn, b_attn);
    for (int t = 0; t < T_STEPS; ++t) {
        // encoder gates: encA @ encB^T
        k_gemm2<<<dim3(13, 32), blk, 0, stream>>>(encA_h, encA_l, KENC, 0,
            encB_h, encB_l, KENC, b_enc_ih, b_enc_hh, gates, GDIM);
        // encoder LSTM: h_enc -> encA[:,688:1088]
        k_lstm<<<dim3((BATCH * ENC + 255) / 256), blk, 0, stream>>>(gates, s_enc,
            encA_h + 688, encA_l + 688, KENC, nullptr, nullptr, 0);
        // mu/logsig: h_enc (encA cols 688+) @ musB^T
        k_gemm2<<<dim3(2, 32), blk, 0, stream>>>(encA_h, encA_l, KENC, 688,
            musB_h, musB_l, KSML, b_cat, nullptr, mus, 200);
        // z -> decA[:,0:100]
        k_zelem<<<dim3((BATCH * ZS + 255) / 256), blk, 0, stream>>>(
            mus, eps + (size_t)t * BATCH * ZS, decA_h, decA_l);
        // decoder gates: decA @ decB^T
        k_gemm2<<<dim3(13, 32), blk, 0, stream>>>(decA_h, decA_l, KDEC, 0,
            decB_h, decB_l, KDEC, b_dec_ih, b_dec_hh, gates, GDIM);
        // decoder LSTM: h_dec -> encA[:,288:688] and decA[:,128:528]
        k_lstm<<<dim3((BATCH * ENC + 255) / 256), blk, 0, stream>>>(gates, s_dec,
            encA_h + 288, encA_l + 288, KENC, decA_h + 128, decA_l + 128, KDEC);
        // write vector: h_dec (encA cols 288+) @ wrtB^T
        k_gemm2<<<dim3(2, 32), blk, 0, stream>>>(encA_h, encA_l, KENC, 288,
            wrtB_h, wrtB_l, KSML, b_write, nullptr, wvec, NF * NF);
        if (t < T_STEPS - 1) {
            // fused: canvas += write(t); r(t+1) = glimpse (shared attention)
            k_wrgl<<<BATCH, blk, 0, stream>>>(x, canvas, encA_h, encA_l,
                                              w_attn, b_attn, wvec);
        } else {
            // final step: write only
            k_write<<<BATCH, blk, 0, stream>>>(encA_h, encA_l, w_attn, b_attn,
                                               wvec, canvas);
        }
    }
}

// Round 8
// 4013.880 us; speedup vs baseline: 1.1447x; 1.1447x over previous
//
#include <hip/hip_runtime.h>
#include <cstdint>
#include <cstddef>

// Problem constants (from reference)
#define T_STEPS 16
#define NF 12            // N attention filters
#define BATCH 4096
#define ZS 100
#define ENC 400
#define DEC 400
#define IMG 4096         // A*B = 64*64
#define GDIM 1600

// GEMM operand geometry (K multiples of 32)
#define KEA 704          // enc A0: [r 0:288 | h_dec 288:688 | pad 688:704]
#define KEB 1120         // enc B: [ih 0:688 | 0 | hh 704:1104 | 0]
#define KDA 128          // dec A0: [z 0:100 | pad]
#define KDB 544          // dec B: [ih 0:100 pad 128 | hh 128:528 | 0]
#define KH  416          // hidden-state ld (h_enc/h_dec ping-pong), real 400
#define NBIG 1664        // padded weight rows (real 1600)
#define NSML 256         // padded rows for mus/wrt B

typedef __attribute__((ext_vector_type(8))) short bfrag;    // 8 x bf16
typedef __attribute__((ext_vector_type(4))) float f32x4;

__device__ __forceinline__ float sigmoidf_(float v) { return 1.f / (1.f + expf(-v)); }

__device__ __forceinline__ float bf2f(unsigned short u) {
    uint32_t x = ((uint32_t)u) << 16;
    return __builtin_bit_cast(float, x);
}

// fp32 -> (bf16_hi, bf16_lo) split, RTN-even. f ~= hi + lo, residual ~2^-18|f|.
__device__ __forceinline__ void split2(float f, unsigned short& h, unsigned short& l) {
    uint32_t u = __builtin_bit_cast(uint32_t, f);
    uint32_t hb = (u + 0x7FFFu + ((u >> 16) & 1u)) >> 16;
    float hf = __builtin_bit_cast(float, hb << 16);
    float r = f - hf;
    uint32_t v = __builtin_bit_cast(uint32_t, r);
    uint32_t lb = (v + 0x7FFFu + ((v >> 16) & 1u)) >> 16;
    h = (unsigned short)hb;
    l = (unsigned short)lb;
}

// LDS-only barrier (keeps global_load_lds prefetch in flight; T4-style)
__device__ __forceinline__ void bar_lds() {
    asm volatile("s_waitcnt lgkmcnt(0)" ::: "memory");
    __builtin_amdgcn_s_barrier();
    __builtin_amdgcn_sched_barrier(0);
}

// ---------------------------------------------------------------------------
// Split-bf16 MFMA GEMM (plain epilogue) for mus/wvec. Single contiguous A.
// Tile 128x128x32, 4 waves 2x2, wave tile 64x64. See R3-R4 notes.
// ---------------------------------------------------------------------------
__global__ __launch_bounds__(256, 2) void k_gemm2(
    const unsigned short* __restrict__ Ah, const unsigned short* __restrict__ Al,
    int lda, int a_off,
    const unsigned short* __restrict__ Bh, const unsigned short* __restrict__ Bl,
    int Kpad,
    const float* __restrict__ b1, const float* __restrict__ b2,
    float* __restrict__ C, int NN)
{
    __shared__ unsigned short lA[2][8 * 512];
    __shared__ unsigned short lB[2][8 * 512];

    const int tid = threadIdx.x;
    const int lane = tid & 63;
    const int wave = tid >> 6;
    const int wr = wave >> 1, wc = wave & 1;
    const int m0 = blockIdx.y * 128;
    const int n0 = blockIdx.x * 128;
    const int rlow = lane & 15;
    const int kg8 = (lane >> 4) * 8;

    const size_t aBase = (size_t)(m0 + rlow) * lda + a_off + kg8;
    const size_t bBase = (size_t)(n0 + rlow) * Kpad + kg8;
    const unsigned short* gsrc;
    unsigned short* ldst;
    size_t stride16;
    if (wave == 0)      { gsrc = Ah + aBase; ldst = &lA[0][0]; stride16 = (size_t)lda * 16; }
    else if (wave == 1) { gsrc = Al + aBase; ldst = &lA[1][0]; stride16 = (size_t)lda * 16; }
    else if (wave == 2) { gsrc = Bh + bBase; ldst = &lB[0][0]; stride16 = (size_t)Kpad * 16; }
    else                { gsrc = Bl + bBase; ldst = &lB[1][0]; stride16 = (size_t)Kpad * 16; }

    f32x4 acc[4][4];
#pragma unroll
    for (int mf = 0; mf < 4; ++mf)
#pragma unroll
        for (int nf = 0; nf < 4; ++nf) acc[mf][nf] = (f32x4){0.f, 0.f, 0.f, 0.f};

    for (int k0 = 0; k0 < Kpad; k0 += 32) {
#pragma unroll
        for (int sub = 0; sub < 8; ++sub) {
            __builtin_amdgcn_global_load_lds(
                (const __attribute__((address_space(1))) void*)(gsrc + (size_t)sub * stride16 + k0),
                (__attribute__((address_space(3))) void*)(ldst + sub * 512), 16, 0, 0);
        }
        __syncthreads();
        bfrag bhf[4], blf[4];
#pragma unroll
        for (int nf = 0; nf < 4; ++nf) {
            bhf[nf] = *(const bfrag*)&lB[0][(wc * 4 + nf) * 512 + lane * 8];
            blf[nf] = *(const bfrag*)&lB[1][(wc * 4 + nf) * 512 + lane * 8];
        }
#pragma unroll
        for (int mf = 0; mf < 4; ++mf) {
            const bfrag ah = *(const bfrag*)&lA[0][(wr * 4 + mf) * 512 + lane * 8];
            const bfrag al = *(const bfrag*)&lA[1][(wr * 4 + mf) * 512 + lane * 8];
#pragma unroll
            for (int nf = 0; nf < 4; ++nf) {
                acc[mf][nf] = __builtin_amdgcn_mfma_f32_16x16x32_bf16(ah, bhf[nf], acc[mf][nf], 0, 0, 0);
                acc[mf][nf] = __builtin_amdgcn_mfma_f32_16x16x32_bf16(ah, blf[nf], acc[mf][nf], 0, 0, 0);
                acc[mf][nf] = __builtin_amdgcn_mfma_f32_16x16x32_bf16(al, bhf[nf], acc[mf][nf], 0, 0, 0);
            }
        }
        __syncthreads();
    }

    const int col = lane & 15;
    const int rowq = (lane >> 4) * 4;
#pragma unroll
    for (int nf = 0; nf < 4; ++nf) {
        const int n = n0 + wc * 64 + nf * 16 + col;
        if (n < NN) {
            float bb = b1[n];
            if (b2) bb += b2[n];
#pragma unroll
            for (int mf = 0; mf < 4; ++mf) {
                const int mbase = m0 + wr * 64 + mf * 16 + rowq;
#pragma unroll
                for (int j = 0; j < 4; ++j)
                    C[(size_t)(mbase + j) * NN + n] = acc[mf][nf][j] + bb;
            }
        }
    }
}

// ---------------------------------------------------------------------------
// GEMM + fused LSTM epilogue. Gate-interleaved weights (row n' = 4u+g), so
// col-block j owns units u in [32j,32j+32) with all 4 gates. Two A pieces
// (k-split KS0, 32-aligned): A0 = [r|h_dec] or [z]; A1 = h ping-pong buffer
// (read old h). Epilogue: acc -> LDS tile (2 halves of 64 rows, reusing
// staging LDS) -> per-cell LSTM -> s update + h bf16 hi/lo to 1-2 dests.
// ---------------------------------------------------------------------------
__global__ __launch_bounds__(256, 2) void k_gemm_lstm(
    const unsigned short* __restrict__ A0h, const unsigned short* __restrict__ A0l,
    int lda0, int KS0,
    const unsigned short* __restrict__ A1h, const unsigned short* __restrict__ A1l,
    int lda1,
    const unsigned short* __restrict__ Bh, const unsigned short* __restrict__ Bl,
    int Kpad,
    const float* __restrict__ b1, const float* __restrict__ b2,
    float* __restrict__ s,
    unsigned short* __restrict__ d1h, unsigned short* __restrict__ d1l, int ld1,
    unsigned short* __restrict__ d2h, unsigned short* __restrict__ d2l, int ld2)
{
    __shared__ __align__(16) uint8_t smem[33792];   // max(lA+lB 32KB, gt 33792B)
    unsigned short* lA0 = (unsigned short*)smem;            // A hi plane (8*512)
    unsigned short* lA1 = lA0 + 4096;                       // A lo
    unsigned short* lB0 = (unsigned short*)(smem + 16384);  // B hi
    unsigned short* lB1 = lB0 + 4096;                       // B lo

    const int tid = threadIdx.x;
    const int lane = tid & 63;
    const int wave = tid >> 6;
    const int wr = wave >> 1, wc = wave & 1;
    const int m0 = blockIdx.y * 128;
    const int n0 = blockIdx.x * 128;
    const int u0 = blockIdx.x * 32;
    const int rlow = lane & 15;
    const int kg8 = (lane >> 4) * 8;
    const int col = lane & 15;
    const int rowq = (lane >> 4) * 4;

    // staging source bases (wave 0: A-hi, 1: A-lo, 2: B-hi, 3: B-lo)
    const unsigned short* pA0;
    const unsigned short* pA1;
    const unsigned short* pB;
    unsigned short* ldst;
    if (wave == 0)      { pA0 = A0h + (size_t)(m0 + rlow) * lda0 + kg8;
                          pA1 = A1h + (size_t)(m0 + rlow) * lda1 + kg8; ldst = lA0; pB = nullptr; }
    else if (wave == 1) { pA0 = A0l + (size_t)(m0 + rlow) * lda0 + kg8;
                          pA1 = A1l + (size_t)(m0 + rlow) * lda1 + kg8; ldst = lA1; pB = nullptr; }
    else if (wave == 2) { pB = Bh + (size_t)(n0 + rlow) * Kpad + kg8; ldst = lB0; pA0 = pA1 = nullptr; }
    else                { pB = Bl + (size_t)(n0 + rlow) * Kpad + kg8; ldst = lB1; pA0 = pA1 = nullptr; }
    const size_t sA0 = (size_t)lda0 * 16, sA1 = (size_t)lda1 * 16, sB = (size_t)Kpad * 16;

    f32x4 acc[4][4];
#pragma unroll
    for (int mf = 0; mf < 4; ++mf)
#pragma unroll
        for (int nf = 0; nf < 4; ++nf) acc[mf][nf] = (f32x4){0.f, 0.f, 0.f, 0.f};

    for (int k0 = 0; k0 < Kpad; k0 += 32) {
        if (wave < 2) {
            const unsigned short* src = (k0 < KS0) ? (pA0 + k0) : (pA1 + (k0 - KS0));
            const size_t st = (k0 < KS0) ? sA0 : sA1;
#pragma unroll
            for (int sub = 0; sub < 8; ++sub)
                __builtin_amdgcn_global_load_lds(
                    (const __attribute__((address_space(1))) void*)(src + (size_t)sub * st),
                    (__attribute__((address_space(3))) void*)(ldst + sub * 512), 16, 0, 0);
        } else {
#pragma unroll
            for (int sub = 0; sub < 8; ++sub)
                __builtin_amdgcn_global_load_lds(
                    (const __attribute__((address_space(1))) void*)(pB + k0 + (size_t)sub * sB),
                    (__attribute__((address_space(3))) void*)(ldst + sub * 512), 16, 0, 0);
        }
        __syncthreads();
        bfrag bhf[4], blf[4];
#pragma unroll
        for (int nf = 0; nf < 4; ++nf) {
            bhf[nf] = *(const bfrag*)&lB0[(wc * 4 + nf) * 512 + lane * 8];
            blf[nf] = *(const bfrag*)&lB1[(wc * 4 + nf) * 512 + lane * 8];
        }
#pragma unroll
        for (int mf = 0; mf < 4; ++mf) {
            const bfrag ah = *(const bfrag*)&lA0[(wr * 4 + mf) * 512 + lane * 8];
            const bfrag al = *(const bfrag*)&lA1[(wr * 4 + mf) * 512 + lane * 8];
#pragma unroll
            for (int nf = 0; nf < 4; ++nf) {
                acc[mf][nf] = __builtin_amdgcn_mfma_f32_16x16x32_bf16(ah, bhf[nf], acc[mf][nf], 0, 0, 0);
                acc[mf][nf] = __builtin_amdgcn_mfma_f32_16x16x32_bf16(ah, blf[nf], acc[mf][nf], 0, 0, 0);
                acc[mf][nf] = __builtin_amdgcn_mfma_f32_16x16x32_bf16(al, bhf[nf], acc[mf][nf], 0, 0, 0);
            }
        }
        __syncthreads();
    }

    // ---- fused LSTM epilogue ----
    float bb[4];
#pragma unroll
    for (int nf = 0; nf < 4; ++nf) {
        const int np = n0 + wc * 64 + nf * 16 + col;
        const int g = np & 3, uu = np >> 2;
        bb[nf] = (uu < 400) ? (b1[g * 400 + uu] + b2[g * 400 + uu]) : 0.f;
    }
    float (*gt)[132] = (float (*)[132])smem;      // 64 x 132 fp32 gate tile
    const int u_l = lane & 31;
    const int ug = u0 + u_l;
    const int mo = lane >> 5;

#pragma unroll
    for (int h = 0; h < 2; ++h) {
        if (wr == h) {
#pragma unroll
            for (int mf = 0; mf < 4; ++mf)
#pragma unroll
                for (int nf = 0; nf < 4; ++nf)
#pragma unroll
                    for (int j = 0; j < 4; ++j)
                        gt[mf * 16 + rowq + j][wc * 64 + nf * 16 + col] = acc[mf][nf][j] + bb[nf];
        }
        __syncthreads();
        if (ug < 400) {
#pragma unroll
            for (int i = 0; i < 8; ++i) {
                const int ml = mo * 32 + wave * 8 + i;
                const size_t row = (size_t)(m0 + h * 64 + ml);
                const f32x4 g4 = *(const f32x4*)&gt[ml][u_l * 4];   // i,f,g,o
                const float cold = s[row * 400 + ug];
                const float c2 = sigmoidf_(g4[1]) * cold + sigmoidf_(g4[0]) * tanhf(g4[2]);
                s[row * 400 + ug] = c2;
                const float hv = sigmoidf_(g4[3]) * tanhf(c2);
                unsigned short hh, hl;
                split2(hv, hh, hl);
                d1h[row * ld1 + ug] = hh;
                d1l[row * ld1 + ug] = hl;
                if (d2h) {
                    d2h[row * ld2 + ug] = hh;
                    d2l[row * ld2 + ug] = hl;
                }
            }
        }
        __syncthreads();
    }
}

// ---------------------------------------------------------------------------
// Weight pre-split; gperm interleaves LSTM gate rows: orig r = g*400+u ->
// dest row = 4u+g.
// ---------------------------------------------------------------------------
__global__ __launch_bounds__(256) void k_fillw(
    const float* __restrict__ src, int rows, int cols,
    unsigned short* __restrict__ dh, unsigned short* __restrict__ dl,
    int ld, int col0, int row0, int gperm)
{
    const int i = blockIdx.x * 256 + threadIdx.x;
    if (i >= rows * cols) return;
    const int r = i / cols, c = i - r * cols;
    const int rr = gperm ? ((r % 400) * 4 + r / 400) : r;
    unsigned short h, l;
    split2(src[i], h, l);
    dh[(size_t)(row0 + rr) * ld + col0 + c] = h;
    dl[(size_t)(row0 + rr) * ld + col0 + c] = l;
}

// ---------------------------------------------------------------------------
// Attention filterbank (full-sync flavor; k_glimpse / k_write, 256 thr).
// ---------------------------------------------------------------------------
__device__ __forceinline__ void attn_compute(
    const float* __restrict__ hd,
    const float* __restrict__ w_attn, const float* __restrict__ b_attn,
    float* __restrict__ p,
    float (* __restrict__ Fx)[68], float (* __restrict__ Fy)[68],
    float* __restrict__ rowinv)
{
    const int t = threadIdx.x;
    const int lane = t & 63, wave = t >> 6;
    for (int o = wave; o < 5; o += 4) {
        float s = 0.f;
        for (int k = lane; k < DEC; k += 64) s += hd[k] * w_attn[o * DEC + k];
#pragma unroll
        for (int off = 32; off; off >>= 1) s += __shfl_down(s, off);
        if (lane == 0) p[o] = s + b_attn[o];
    }
    __syncthreads();
    const float gx = 32.5f * (p[0] + 1.f);
    const float gy = 32.5f * (p[1] + 1.f);
    const float sigma2 = expf(p[2]);
    const float delta = (63.f / 11.f) * expf(p[3]);
    const float inv2s = 1.f / (2.f * sigma2);
    for (int e = t; e < NF * 64; e += 256) {
        const int n = e >> 6, a = e & 63;
        const float mu_x = ((float)n - 6.5f) * delta + gx;
        const float mu_y = ((float)n - 6.5f) * delta + gy;
        const float tx = ((float)a - mu_x) * inv2s;
        const float ty = ((float)a - mu_y) * inv2s;
        Fx[n][a] = expf(-tx * tx);
        Fy[n][a] = expf(-ty * ty);
    }
    __syncthreads();
    for (int rix = wave; rix < 24; rix += 4) {
        const float* row = (rix < 12) ? &Fx[rix][0] : &Fy[rix - 12][0];
        float s = row[lane];
#pragma unroll
        for (int off = 32; off; off >>= 1) s += __shfl_down(s, off);
        if (lane == 0) rowinv[rix] = 1.f / (s + 1e-9f);
    }
    __syncthreads();
    for (int e = t; e < NF * 64; e += 256) {
        const int n = e >> 6, a = e & 63;
        Fx[n][a] *= rowinv[n];
        Fy[n][a] *= rowinv[12 + n];
    }
}

// ---------------------------------------------------------------------------
// Glimpse (step 0 only, 256 thr): r(0) -> encA cols 0:288.
// ---------------------------------------------------------------------------
__global__ __launch_bounds__(256) void k_glimpse(
    const float* __restrict__ x, const float* __restrict__ c,
    unsigned short* __restrict__ eAh, unsigned short* __restrict__ eAl,
    const float* __restrict__ w_attn, const float* __restrict__ b_attn)
{
    __shared__ __align__(16) float hd[DEC];
    __shared__ __align__(16) float p[8];
    __shared__ __align__(16) float Fx[NF][68], Fy[NF][68];
    __shared__ __align__(16) float rowinv[24];
    __shared__ __align__(16) float img[IMG], imgh[IMG];
    __shared__ __align__(16) float tmp1[NF][68], tmp2[NF][68];
    const int item = blockIdx.x;
    const int t = threadIdx.x;
    const size_t arow = (size_t)item * KEA;

    for (int i = t; i < DEC; i += 256)
        hd[i] = bf2f(eAh[arow + 288 + i]) + bf2f(eAl[arow + 288 + i]);
    __syncthreads();
    attn_compute(hd, w_attn, b_attn, p, Fx, Fy, rowinv);

    for (int i = t; i < IMG; i += 256) {
        const float xv = x[(size_t)item * IMG + i];
        const float cv = c[(size_t)item * IMG + i];
        img[i] = xv;
        imgh[i] = xv - sigmoidf_(cv);
    }
    __syncthreads();
    const float gamma = expf(p[4]);

    if (t < 192) {
        const int n = t >> 4, a0 = (t & 15) * 4;
        float s10 = 0, s11 = 0, s12 = 0, s13 = 0;
        float s20 = 0, s21 = 0, s22 = 0, s23 = 0;
        for (int Bi = 0; Bi < 64; ++Bi) {
            const float fy = Fy[n][Bi];
            const float4 v1 = *(const float4*)&img[Bi * 64 + a0];
            const float4 v2 = *(const float4*)&imgh[Bi * 64 + a0];
            s10 += fy * v1.x; s11 += fy * v1.y; s12 += fy * v1.z; s13 += fy * v1.w;
            s20 += fy * v2.x; s21 += fy * v2.y; s22 += fy * v2.z; s23 += fy * v2.w;
        }
        *(float4*)&tmp1[n][a0] = make_float4(s10, s11, s12, s13);
        *(float4*)&tmp2[n][a0] = make_float4(s20, s21, s22, s23);
    }
    __syncthreads();

    for (int e = t; e < 2 * NF * NF; e += 256) {
        const int which = e / 144;
        const int idx = e - which * 144;
        const int n = idx / 12, m = idx - (idx / 12) * 12;
        const float (*tp)[68] = which ? tmp2 : tmp1;
        const float4* tv = (const float4*)&tp[n][0];
        const float4* fv = (const float4*)&Fx[m][0];
        float s = 0.f;
#pragma unroll
        for (int a4 = 0; a4 < 16; ++a4) {
            const float4 tvv = tv[a4], fvv = fv[a4];
            s += tvv.x * fvv.x + tvv.y * fvv.y + tvv.z * fvv.z + tvv.w * fvv.w;
        }
        unsigned short vh, vl;
        split2(s * gamma, vh, vl);
        eAh[arow + e] = vh;
        eAl[arow + e] = vl;
    }
}

// ---------------------------------------------------------------------------
// FUSED write(t) + glimpse(t+1), 512 threads (R6 math; 2x waves/CU).
// ---------------------------------------------------------------------------
__global__ __launch_bounds__(512) void k_wrgl(
    const float* __restrict__ x, float* __restrict__ c,
    unsigned short* __restrict__ eAh, unsigned short* __restrict__ eAl,
    const float* __restrict__ w_attn, const float* __restrict__ b_attn,
    const float* __restrict__ wvec)
{
    __shared__ __align__(16) float xx[64][64];    // x (16 KiB, async-filled)
    __shared__ __align__(16) float gg[64][64];    // x_hat (16 KiB)
    __shared__ __align__(16) float hd[DEC];
    __shared__ __align__(16) float p[8];
    __shared__ __align__(16) float Fx[NF][68], Fy[NF][68];
    __shared__ __align__(16) float rowinv[24];
    __shared__ __align__(16) float wsv[NF * NF];
    __shared__ __align__(16) float u[64][13];
    __shared__ __align__(16) float tmp[2][NF][68];
    const int item = blockIdx.x;
    const int t = threadIdx.x;              // 0..511
    const int lane = t & 63, wave = t >> 6; // 8 waves
    const size_t arow = (size_t)item * KEA;

    // --- p0: canvas -> regs; x -> LDS async; h_dec/wvec -> LDS ---
    float4 cv4[2];
#pragma unroll
    for (int j = 0; j < 2; ++j)
        cv4[j] = *(const float4*)&c[(size_t)item * IMG + j * 2048 + t * 4];
    {
        const float* xsrc = x + (size_t)item * IMG + wave * 512 + lane * 4;
        float* xdst = &xx[0][0] + wave * 512;
#pragma unroll
        for (int j = 0; j < 2; ++j)
            __builtin_amdgcn_global_load_lds(
                (const __attribute__((address_space(1))) void*)(xsrc + j * 256),
                (__attribute__((address_space(3))) void*)(xdst + j * 256), 16, 0, 0);
    }
    if (t < DEC) hd[t] = bf2f(eAh[arow + 288 + t]) + bf2f(eAl[arow + 288 + t]);
    if (t < NF * NF) wsv[t] = wvec[(size_t)item * (NF * NF) + t];
    bar_lds();

    // --- p1: attention (lgkm-only barriers) ---
    for (int o = wave; o < 5; o += 8) {
        float s = 0.f;
        for (int k = lane; k < DEC; k += 64) s += hd[k] * w_attn[o * DEC + k];
#pragma unroll
        for (int off = 32; off; off >>= 1) s += __shfl_down(s, off);
        if (lane == 0) p[o] = s + b_attn[o];
    }
    bar_lds();
    {
        const float gx = 32.5f * (p[0] + 1.f);
        const float gy = 32.5f * (p[1] + 1.f);
        const float sigma2 = expf(p[2]);
        const float delta = (63.f / 11.f) * expf(p[3]);
        const float inv2s = 1.f / (2.f * sigma2);
        for (int e = t; e < NF * 64; e += 512) {
            const int n = e >> 6, a = e & 63;
            const float mu_x = ((float)n - 6.5f) * delta + gx;
            const float mu_y = ((float)n - 6.5f) * delta + gy;
            const float tx = ((float)a - mu_x) * inv2s;
            const float ty = ((float)a - mu_y) * inv2s;
            Fx[n][a] = expf(-tx * tx);
            Fy[n][a] = expf(-ty * ty);
        }
    }
    bar_lds();
    for (int rix = wave; rix < 24; rix += 8) {
        const float* row = (rix < 12) ? &Fx[rix][0] : &Fy[rix - 12][0];
        float s = row[lane];
#pragma unroll
        for (int off = 32; off; off >>= 1) s += __shfl_down(s, off);
        if (lane == 0) rowinv[rix] = 1.f / (s + 1e-9f);
    }
    bar_lds();
    for (int e = t; e < NF * 64; e += 512) {
        const int n = e >> 6, a = e & 63;
        Fx[n][a] *= rowinv[n];
        Fy[n][a] *= rowinv[12 + n];
    }
    bar_lds();
    const float gamma = expf(p[4]);
    const float ginv = 1.f / gamma;
    for (int e = t; e < 64 * NF; e += 512) {
        const int Bb = e / 12, m = e - (e / 12) * 12;
        float s = 0.f;
#pragma unroll
        for (int n = 0; n < 12; ++n) s += Fy[n][Bb] * wsv[n * 12 + m];
        u[Bb][m] = s;
    }

    // --- p2: canvas update (regs) + imgh -> gg (full sync drains x) ---
    __syncthreads();
#pragma unroll
    for (int j = 0; j < 2; ++j) {
        const int i0 = j * 2048 + t * 4;
        const int Bb = i0 >> 6, a0 = i0 & 63;
        float s0 = 0, s1 = 0, s2 = 0, s3 = 0;
#pragma unroll
        for (int m = 0; m < 12; ++m) {
            const float um = u[Bb][m];
            s0 += um * Fx[m][a0];     s1 += um * Fx[m][a0 + 1];
            s2 += um * Fx[m][a0 + 2]; s3 += um * Fx[m][a0 + 3];
        }
        const float4 cn = make_float4(cv4[j].x + s0 * ginv, cv4[j].y + s1 * ginv,
                                      cv4[j].z + s2 * ginv, cv4[j].w + s3 * ginv);
        *(float4*)&c[(size_t)item * IMG + i0] = cn;
        const float4 xv = *(const float4*)&xx[Bb][a0];
        *(float4*)&gg[Bb][a0] = make_float4(
            xv.x - sigmoidf_(cn.x), xv.y - sigmoidf_(cn.y),
            xv.z - sigmoidf_(cn.z), xv.w - sigmoidf_(cn.w));
    }
    bar_lds();

    // --- p3: glimpse contraction (384 threads: 2 images x 192) ---
    if (t < 384) {
        const int which = t / 192;
        const int r2 = t - which * 192;
        const int n = r2 >> 4, a0 = (r2 & 15) * 4;
        const float (*src)[64] = which ? gg : xx;
        float s0 = 0, s1 = 0, s2 = 0, s3 = 0;
        for (int Bi = 0; Bi < 64; ++Bi) {
            const float fy = Fy[n][Bi];
            const float4 v = *(const float4*)&src[Bi][a0];
            s0 += fy * v.x; s1 += fy * v.y; s2 += fy * v.z; s3 += fy * v.w;
        }
        *(float4*)&tmp[which][n][a0] = make_float4(s0, s1, s2, s3);
    }
    bar_lds();

    // --- p4: r = gamma * tmp @ Fx^T -> encA bf16 hi/lo (288 threads) ---
    if (t < 2 * NF * NF) {
        const int which = t / 144;
        const int idx = t - which * 144;
        const int n = idx / 12, m = idx - (idx / 12) * 12;
        const float4* tv = (const float4*)&tmp[which][n][0];
        const float4* fv = (const float4*)&Fx[m][0];
        float s = 0.f;
#pragma unroll
        for (int a4 = 0; a4 < 16; ++a4) {
            const float4 tvv = tv[a4], fvv = fv[a4];
            s += tvv.x * fvv.x + tvv.y * fvv.y + tvv.z * fvv.z + tvv.w * fvv.w;
        }
        unsigned short vh, vl;
        split2(s * gamma, vh, vl);
        eAh[arow + t] = vh;
        eAl[arow + t] = vl;
    }
}

// z = mu + exp(logsig)*eps -> decA cols 0:100 (hi/lo), ld KDA
__global__ __launch_bounds__(256) void k_zelem(
    const float* __restrict__ mus, const float* __restrict__ eps_t,
    unsigned short* __restrict__ dzh, unsigned short* __restrict__ dzl)
{
    const int idx = blockIdx.x * 256 + threadIdx.x;
    if (idx >= BATCH * ZS) return;
    const int m = idx / ZS, o = idx - m * ZS;
    const float zv = mus[(size_t)m * 200 + o] + expf(mus[(size_t)m * 200 + 100 + o]) * eps_t[idx];
    unsigned short h, l;
    split2(zv, h, l);
    dzh[(size_t)m * KDA + o] = h;
    dzl[(size_t)m * KDA + o] = l;
}

// ---------------------------------------------------------------------------
// Write (final step only, 256 thr): c += Fy^T @ w @ Fx / gamma.
// ---------------------------------------------------------------------------
__global__ __launch_bounds__(256) void k_write(
    const unsigned short* __restrict__ eAh, const unsigned short* __restrict__ eAl,
    const float* __restrict__ w_attn, const float* __restrict__ b_attn,
    const float* __restrict__ wvec,
    float* __restrict__ c)
{
    __shared__ __align__(16) float hd[DEC];
    __shared__ __align__(16) float p[8];
    __shared__ __align__(16) float Fx[NF][68], Fy[NF][68];
    __shared__ __align__(16) float rowinv[24];
    __shared__ __align__(16) float wsv[NF * NF];
    __shared__ __align__(16) float u[64][13];
    const int item = blockIdx.x;
    const int t = threadIdx.x;
    const size_t arow = (size_t)item * KEA;

    for (int i = t; i < DEC; i += 256)
        hd[i] = bf2f(eAh[arow + 288 + i]) + bf2f(eAl[arow + 288 + i]);
    if (t < NF * NF) wsv[t] = wvec[(size_t)item * (NF * NF) + t];
    __syncthreads();
    attn_compute(hd, w_attn, b_attn, p, Fx, Fy, rowinv);
    __syncthreads();
    const float ginv = 1.f / expf(p[4]);

    for (int e = t; e < 64 * NF; e += 256) {
        const int Bb = e / 12, m = e - (e / 12) * 12;
        float s = 0.f;
#pragma unroll
        for (int n = 0; n < 12; ++n) s += Fy[n][Bb] * wsv[n * 12 + m];
        u[Bb][m] = s;
    }
    __syncthreads();
    for (int i = t; i < IMG; i += 256) {
        const int Bb = i >> 6, a = i & 63;
        float s = 0.f;
#pragma unroll
        for (int m = 0; m < 12; ++m) s += u[Bb][m] * Fx[m][a];
        c[(size_t)item * IMG + i] += s * ginv;
    }
}

// ---------------------------------------------------------------------------
extern "C" void kernel_launch(void* const* d_in, const int* in_sizes, int n_in,
                              void* d_out, int out_size, void* d_ws, size_t ws_size,
                              hipStream_t stream)
{
    const float* x        = (const float*)d_in[0];
    const float* eps      = (const float*)d_in[1];
    const float* w_enc_ih = (const float*)d_in[2];
    const float* w_enc_hh = (const float*)d_in[3];
    const float* b_enc_ih = (const float*)d_in[4];
    const float* b_enc_hh = (const float*)d_in[5];
    const float* w_dec_ih = (const float*)d_in[6];
    const float* w_dec_hh = (const float*)d_in[7];
    const float* b_dec_ih = (const float*)d_in[8];
    const float* b_dec_hh = (const float*)d_in[9];
    const float* w_mu     = (const float*)d_in[10];
    const float* b_mu     = (const float*)d_in[11];
    const float* w_sig    = (const float*)d_in[12];
    const float* b_sig    = (const float*)d_in[13];
    const float* w_attn   = (const float*)d_in[14];
    const float* b_attn   = (const float*)d_in[15];
    const float* w_write  = (const float*)d_in[16];
    const float* b_write  = (const float*)d_in[17];

    float* canvas = (float*)d_out;

    // ---- workspace layout ----
    uint8_t* p = (uint8_t*)d_ws;
    auto nextu = [&](size_t elems) {
        unsigned short* r = (unsigned short*)p;
        p += (elems * 2 + 255) & ~(size_t)255;
        return r;
    };
    auto nextf = [&](size_t elems) {
        float* r = (float*)p;
        p += (elems * 4 + 255) & ~(size_t)255;
        return r;
    };
    uint8_t* zstart = p;
    unsigned short* encA_h = nextu((size_t)(BATCH + 1) * KEA);
    unsigned short* encA_l = nextu((size_t)(BATCH + 1) * KEA);
    unsigned short* decA_h = nextu((size_t)(BATCH + 1) * KDA);
    unsigned short* decA_l = nextu((size_t)(BATCH + 1) * KDA);
    unsigned short* hencH[2], *hencL[2], *hdecH[2], *hdecL[2];
    for (int i = 0; i < 2; ++i) {
        hencH[i] = nextu((size_t)(BATCH + 1) * KH);
        hencL[i] = nextu((size_t)(BATCH + 1) * KH);
        hdecH[i] = nextu((size_t)(BATCH + 1) * KH);
        hdecL[i] = nextu((size_t)(BATCH + 1) * KH);
    }
    unsigned short* encB_h = nextu((size_t)NBIG * KEB);
    unsigned short* encB_l = nextu((size_t)NBIG * KEB);
    unsigned short* decB_h = nextu((size_t)NBIG * KDB);
    unsigned short* decB_l = nextu((size_t)NBIG * KDB);
    unsigned short* musB_h = nextu((size_t)NSML * KH);
    unsigned short* musB_l = nextu((size_t)NSML * KH);
    unsigned short* wrtB_h = nextu((size_t)NSML * KH);
    unsigned short* wrtB_l = nextu((size_t)NSML * KH);
    float* s_enc = nextf((size_t)BATCH * ENC);
    float* s_dec = nextf((size_t)BATCH * DEC);
    float* b_cat = nextf(256);
    uint8_t* zend = p;
    float* mus   = nextf((size_t)BATCH * 200);
    float* wvec  = nextf((size_t)BATCH * (NF * NF));

    hipMemsetAsync(zstart, 0, (size_t)(zend - zstart), stream);
    hipMemsetAsync(canvas, 0, (size_t)BATCH * IMG * sizeof(float), stream);

    auto fill = [&](const float* src, int rows, int cols,
                    unsigned short* dh, unsigned short* dl, int ld, int col0,
                    int row0, int gperm) {
        k_fillw<<<dim3((rows * cols + 255) / 256), 256, 0, stream>>>(
            src, rows, cols, dh, dl, ld, col0, row0, gperm);
    };
    fill(w_enc_ih, 1600, 688, encB_h, encB_l, KEB, 0,   0,   1);
    fill(w_enc_hh, 1600, 400, encB_h, encB_l, KEB, 704, 0,   1);
    fill(w_dec_ih, 1600, 100, decB_h, decB_l, KDB, 0,   0,   1);
    fill(w_dec_hh, 1600, 400, decB_h, decB_l, KDB, 128, 0,   1);
    fill(w_mu,     100, 400, musB_h, musB_l, KH,  0,   0,   0);
    fill(w_sig,    100, 400, musB_h, musB_l, KH,  0,   100, 0);
    fill(w_write,  144, 400, wrtB_h, wrtB_l, KH,  0,   0,   0);
    hipMemcpyAsync(b_cat,       b_mu,  100 * 4, hipMemcpyDeviceToDevice, stream);
    hipMemcpyAsync(b_cat + 100, b_sig, 100 * 4, hipMemcpyDeviceToDevice, stream);

    // glimpse for step 0 (h_dec=0, canvas=0) -> r(0)
    k_glimpse<<<BATCH, 256, 0, stream>>>(x, canvas, encA_h, encA_l, w_attn, b_attn);
    for (int t = 0; t < T_STEPS; ++t) {
        const int cur = t & 1, nxt = cur ^ 1;
        // encoder gates + LSTM: A=[encA | henc[cur]], epilogue -> henc[nxt]
        k_gemm_lstm<<<dim3(13, 32), 256, 0, stream>>>(
            encA_h, encA_l, KEA, 704, hencH[cur], hencL[cur], KH,
            encB_h, encB_l, KEB, b_enc_ih, b_enc_hh, s_enc,
            hencH[nxt], hencL[nxt], KH, nullptr, nullptr, 0);
        // mu/logsig: henc[nxt] @ musB^T
        k_gemm2<<<dim3(2, 32), 256, 0, stream>>>(hencH[nxt], hencL[nxt], KH, 0,
            musB_h, musB_l, KH, b_cat, nullptr, mus, 200);
        // z -> decA[:,0:100]
        k_zelem<<<dim3((BATCH * ZS + 255) / 256), 256, 0, stream>>>(
            mus, eps + (size_t)t * BATCH * ZS, decA_h, decA_l);
        // decoder gates + LSTM: A=[decA | hdec[cur]], epilogue -> encA+288 and hdec[nxt]
        k_gemm_lstm<<<dim3(13, 32), 256, 0, stream>>>(
            decA_h, decA_l, KDA, 128, hdecH[cur], hdecL[cur], KH,
            decB_h, decB_l, KDB, b_dec_ih, b_dec_hh, s_dec,
            encA_h + 288, encA_l + 288, KEA, hdecH[nxt], hdecL[nxt], KH);
        // write vector: h_dec (encA cols 288:704) @ wrtB^T
        k_gemm2<<<dim3(2, 32), 256, 0, stream>>>(encA_h, encA_l, KEA, 288,
            wrtB_h, wrtB_l, KH, b_write, nullptr, wvec, NF * NF);
        if (t < T_STEPS - 1) {
            k_wrgl<<<BATCH, 512, 0, stream>>>(x, canvas, encA_h, encA_l,
                                              w_attn, b_attn, wvec);
        } else {
            k_write<<<BATCH, 256, 0, stream>>>(encA_h, encA_l, w_attn, b_attn,
                                               wvec, canvas);
        }
    }
}